// Round 5
// baseline (457.042 us; speedup 1.0000x reference)
//
#include <hip/hip_runtime.h>
#include <hip/hip_bf16.h>
#include <math.h>

#define NE    8
#define KTOP  2
#define CDIM  1024
#define HDIM  4096
#define NTOK  8192
#define CAPE  1280
#define NSLOT (NTOK * KTOP)

typedef __bf16 bf16x8 __attribute__((ext_vector_type(8)));
typedef __bf16 bf16x4 __attribute__((ext_vector_type(4)));
typedef __bf16 bf16x2 __attribute__((ext_vector_type(2)));
typedef float  f32x4  __attribute__((ext_vector_type(4)));

#define GAS __attribute__((address_space(1)))
#define LAS __attribute__((address_space(3)))

// ---------------------------------------------------------------------------
// Transposing fp32 -> bf16 weight conversion: src [E][R][Cc] -> dst [E][Cc][R]
// ---------------------------------------------------------------------------
__global__ __launch_bounds__(256) void k_transpose_bf16(
    const float* __restrict__ src, __bf16* __restrict__ dst, int R, int Cc)
{
    __shared__ float tile[32][33];
    const int e  = blockIdx.z;
    const int cb = blockIdx.x * 32;
    const int rb = blockIdx.y * 32;
    const int t  = threadIdx.x;
    const int tx = t & 31, ty = t >> 5;
    const float* s = src + (size_t)e * R * Cc;
    __bf16*      d = dst + (size_t)e * R * Cc;
#pragma unroll
    for (int i = 0; i < 32; i += 8)
        tile[ty + i][tx] = s[(size_t)(rb + ty + i) * Cc + cb + tx];
    __syncthreads();
    const int op  = t & 15;      // src-row pair
    const int oc0 = t >> 4;      // out-row base (0..15)
#pragma unroll
    for (int j = 0; j < 2; ++j) {
        const int oc = oc0 + j * 16;
        bf16x2 v;
        v[0] = (__bf16)tile[op * 2][oc];
        v[1] = (__bf16)tile[op * 2 + 1][oc];
        *(bf16x2*)(d + (size_t)(cb + oc) * R + rb + op * 2) = v;
    }
}

// ---------------------------------------------------------------------------
// Router: fp32 logits -> softmax -> top2 -> normalized gates. 1 wave = 1 token.
// ---------------------------------------------------------------------------
__global__ __launch_bounds__(256) void k_router(
    const float* __restrict__ x, const float* __restrict__ rw,
    const float* __restrict__ rb, float* __restrict__ probs,
    float* __restrict__ gates, int* __restrict__ tidx)
{
    __shared__ float rws[NE * CDIM];
    const int tid = threadIdx.x;
    for (int i = tid; i < NE * CDIM / 4; i += 256)
        ((float4*)rws)[i] = ((const float4*)rw)[i];
    __syncthreads();

    const int wave = tid >> 6, lane = tid & 63;
    const int n = blockIdx.x * 4 + wave;
    const float* xr = x + (size_t)n * CDIM;

    float acc[NE];
#pragma unroll
    for (int e = 0; e < NE; ++e) acc[e] = 0.f;
    for (int j = 0; j < CDIM / 64; ++j) {
        const float xv = xr[j * 64 + lane];
#pragma unroll
        for (int e = 0; e < NE; ++e) acc[e] += xv * rws[e * CDIM + j * 64 + lane];
    }
#pragma unroll
    for (int off = 32; off > 0; off >>= 1) {
#pragma unroll
        for (int e = 0; e < NE; ++e) acc[e] += __shfl_down(acc[e], off);
    }
    if (lane == 0) {
        float mx = -1e30f;
#pragma unroll
        for (int e = 0; e < NE; ++e) { acc[e] += rb[e]; mx = fmaxf(mx, acc[e]); }
        float p[NE], s = 0.f;
#pragma unroll
        for (int e = 0; e < NE; ++e) { p[e] = expf(acc[e] - mx); s += p[e]; }
        const float inv = 1.f / s;
#pragma unroll
        for (int e = 0; e < NE; ++e) { p[e] *= inv; probs[(size_t)n * NE + e] = p[e]; }
        int   i1 = 0;  float v1 = p[0];
        int   i2 = -1; float v2 = -1.f;
#pragma unroll
        for (int e = 1; e < NE; ++e) {
            if (p[e] > v1)      { v2 = v1; i2 = i1; v1 = p[e]; i1 = e; }
            else if (p[e] > v2) { v2 = p[e]; i2 = e; }
        }
        const float gs = 1.f / (v1 + v2);
        gates[n * 2 + 0] = v1 * gs;  gates[n * 2 + 1] = v2 * gs;
        tidx[n * 2 + 0]  = i1;       tidx[n * 2 + 1]  = i2;
    }
}

// ---------------------------------------------------------------------------
// Single-block scan: exact slot-order ranks, capacity drop, tok_buf, aux loss.
// ---------------------------------------------------------------------------
__global__ __launch_bounds__(256) void k_scan(
    const int* __restrict__ tidx, const float* __restrict__ probs,
    int* __restrict__ slot, int* __restrict__ tok, float* __restrict__ d_aux)
{
    __shared__ int   lcnt[256][NE];
    __shared__ float ps[256][NE];
    const int t = threadIdx.x;

    for (int i = t; i < NE * CAPE; i += 256) tok[i] = 0;

    int c8[NE];
#pragma unroll
    for (int e = 0; e < NE; ++e) c8[e] = 0;
    const int per  = NSLOT / 256;   // 64
    const int base = t * per;
    for (int s = 0; s < per; ++s) c8[tidx[base + s]]++;
#pragma unroll
    for (int e = 0; e < NE; ++e) lcnt[t][e] = c8[e];

    float f8[NE];
#pragma unroll
    for (int e = 0; e < NE; ++e) f8[e] = 0.f;
    for (int n = t; n < NTOK; n += 256) {
        const float4 a = *(const float4*)(probs + (size_t)n * NE);
        const float4 b = *(const float4*)(probs + (size_t)n * NE + 4);
        f8[0] += a.x; f8[1] += a.y; f8[2] += a.z; f8[3] += a.w;
        f8[4] += b.x; f8[5] += b.y; f8[6] += b.z; f8[7] += b.w;
    }
#pragma unroll
    for (int e = 0; e < NE; ++e) ps[t][e] = f8[e];

    __syncthreads();

    int pre[NE], tot[NE];
#pragma unroll
    for (int e = 0; e < NE; ++e) { pre[e] = 0; tot[e] = 0; }
    for (int tt = 0; tt < 256; ++tt) {
#pragma unroll
        for (int e = 0; e < NE; ++e) {
            const int v = lcnt[tt][e];
            tot[e] += v;
            if (tt < t) pre[e] += v;
        }
    }
    for (int s = 0; s < per; ++s) {
        const int sg = base + s;
        const int e  = tidx[sg];
        const int p  = pre[e]++;
        if (p < CAPE) { slot[sg] = e * CAPE + p; tok[e * CAPE + p] = sg >> 1; }
        else          { slot[sg] = -1; }
    }
    if (t == 0) {
        float imp[NE], isum = 0.f, ld[NE], lsum = 0.f;
#pragma unroll
        for (int e = 0; e < NE; ++e) {
            float v = 0.f;
            for (int tt = 0; tt < 256; ++tt) v += ps[tt][e];
            imp[e] = v; isum += v;
        }
#pragma unroll
        for (int e = 0; e < NE; ++e) { ld[e] = fminf((float)tot[e], (float)CAPE); lsum += ld[e]; }
        float aux = 0.f;
#pragma unroll
        for (int e = 0; e < NE; ++e) aux += (imp[e] / isum) * (ld[e] / lsum);
        *d_aux = aux * (float)(NE * NE);
    }
}

// ---------------------------------------------------------------------------
// Gather tokens into dense per-expert buffers, fp32 -> bf16.
// ---------------------------------------------------------------------------
__global__ __launch_bounds__(256) void k_gather(
    const float* __restrict__ x, const int* __restrict__ tok,
    __bf16* __restrict__ inp)
{
    const int row = blockIdx.x;
    const int t   = threadIdx.x;
    const int tk  = tok[row];
    const float4 v = ((const float4*)(x + (size_t)tk * CDIM))[t];
    bf16x4 o;
    o[0] = (__bf16)v.x; o[1] = (__bf16)v.y; o[2] = (__bf16)v.z; o[3] = (__bf16)v.w;
    *(bf16x4*)(inp + (size_t)row * CDIM + t * 4) = o;
}

// ---------------------------------------------------------------------------
// 256x256 4-wave MFMA GEMM, per-wave 128x128 output (LDS-traffic-minimal).
//   1 wave/SIMD, acc[8][8] f32x4 (256 VGPR, __launch_bounds__(256,1)).
//   Per K-tile(64): reads split in 4 quadrant groups (12/4/12/4 ds_read_b128),
//   each 32-MFMA cluster gated by counted lgkmcnt(4/12/4/0) so next group's
//   LDS service hides under current MFMA. Staging (16 global_load_lds) issued
//   mid-tile, drained by vmcnt(0) ~2000cyc later (free). 1 barrier/K-tile.
//   LDS 128KiB: buf{0,1} x (A 32KB + B 32KB). XOR-swizzle byte^=(row&7)<<4
//   via pre-swizzled global source (linear LDS dest).
// ---------------------------------------------------------------------------
#define MFMA_BF16 __builtin_amdgcn_mfma_f32_16x16x32_bf16
#define DSR(dst, addr, IMM) \
    asm volatile("ds_read_b128 %0, %1 offset:" #IMM : "=v"(dst) : "v"(addr))
#define WLG(N)  asm volatile("s_waitcnt lgkmcnt(" #N ")" ::: "memory")
#define WVM0()  asm volatile("s_waitcnt vmcnt(0)" ::: "memory")
#define SB0()   __builtin_amdgcn_sched_barrier(0)

// 32 MFMA: n in [NB,NB+4) x m in [0,8), frags FA/FB
#define QUAD(FA, FB, NB)                                                      \
    _Pragma("unroll")                                                         \
    for (int n = 0; n < 4; ++n) {                                             \
        _Pragma("unroll")                                                     \
        for (int m = 0; m < 8; ++m)                                           \
            acc[m][(NB) + n] =                                                \
                MFMA_BF16(FB[(NB) + n], FA[m], acc[m][(NB) + n], 0, 0, 0);    \
    }                                                                         \
    SB0();

#define RD_A(FA, VA)                                                          \
    DSR(FA[0], VA, 0);     DSR(FA[1], VA, 2048);  DSR(FA[2], VA, 4096);       \
    DSR(FA[3], VA, 6144);  DSR(FA[4], VA, 8192);  DSR(FA[5], VA, 10240);      \
    DSR(FA[6], VA, 12288); DSR(FA[7], VA, 14336);

template <bool GELU>
__global__ __launch_bounds__(256, 1) void k_gemm4(
    const __bf16* __restrict__ Aall, const __bf16* __restrict__ Ball,
    const float* __restrict__ biasAll, __bf16* __restrict__ Call,
    int Ktot, int Ntot, int NBN, int mtPerE)
{
    __shared__ char lds[131072];   // buf: 65536 each; A @0, B @32768

    const int NK  = Ktot >> 6;
    const int cpx = gridDim.x >> 3;                 // grid % 8 == 0 by caller
    const int id  = blockIdx.x;
    const int sid = (id & 7) * cpx + (id >> 3);     // bijective XCD swizzle
    const int bm  = sid / NBN, bn = sid % NBN;
    const int e   = bm / mtPerE;

    const size_t row0 = (size_t)bm * 256;
    const int    col0 = bn * 256;

    const int tid = threadIdx.x;
    const int w   = tid >> 6, l = tid & 63;
    const int lr  = l & 15, hi = l >> 4;

    // ---- staging constants: thread t covers chunk c = 256h + t,
    //      row = c>>3 = (t>>3)+32h, k-slot = t&7, pre-swizzled by row&7 ----
    const int srow = tid >> 3;                              // 0..31
    const int kf   = ((tid & 7) ^ (srow & 7)) << 3;         // swizzled k elems
    const __bf16* pA = Aall + (row0 + srow) * (size_t)Ktot + kf;
    const __bf16* pB = Ball + ((size_t)e * Ntot + col0 + srow) * (size_t)Ktot + kf;
    const size_t rstep = (size_t)32 * Ktot;
    const unsigned L0  = (unsigned)(size_t)(LAS char*)lds;
    const unsigned dA0 = L0 + w * 1024;                     // HW adds lane*16
    const unsigned dB0 = L0 + 32768 + w * 1024;

    auto STAGE = [&](unsigned bo, int kt) {
        const __bf16* ga = pA + (size_t)kt * 64;
        const __bf16* gb = pB + (size_t)kt * 64;
#pragma unroll
        for (int h = 0; h < 8; ++h) {
            __builtin_amdgcn_global_load_lds(
                (const GAS void*)(ga + h * rstep),
                (LAS void*)(size_t)(dA0 + bo + h * 4096), 16, 0, 0);
            __builtin_amdgcn_global_load_lds(
                (const GAS void*)(gb + h * rstep),
                (LAS void*)(size_t)(dB0 + bo + h * 4096), 16, 0, 0);
        }
    };

    // ---- ds_read lane constants (swizzled) ----
    const unsigned swz = (l & 7) << 4;
    const unsigned kb0 = ((unsigned)(hi << 4)) ^ swz;        // k-half 0
    const unsigned kb1 = ((unsigned)(64 + (hi << 4))) ^ swz; // k-half 1
    const unsigned AbaseR = L0 + (unsigned)(((w >> 1) * 128 + lr) * 128);
    const unsigned BbaseR = L0 + 32768 + (unsigned)(((w & 1) * 128 + lr) * 128);

    // ---- prologue: stage tile 0 into buf 0 ----
    STAGE(0, 0);
    WVM0();
    __builtin_amdgcn_s_barrier();
    SB0();

    f32x4 acc[8][8] = {};
    bf16x8 fa0[8], fa1[8], fb0[8], fb1[8];

    unsigned bo = 0;
    for (int T = 0; T < NK; ++T) {
        const unsigned va0 = AbaseR + bo + kb0, va1 = AbaseR + bo + kb1;
        const unsigned vb0 = BbaseR + bo + kb0, vb1 = BbaseR + bo + kb1;

        // q0 issue: fa0 (8) + fb0[0..3] (4) = 12 reads
        RD_A(fa0, va0)
        DSR(fb0[0], vb0, 0);    DSR(fb0[1], vb0, 2048);
        DSR(fb0[2], vb0, 4096); DSR(fb0[3], vb0, 6144);
        // q1 issue: fb0[4..7] (4)
        DSR(fb0[4], vb0, 8192);  DSR(fb0[5], vb0, 10240);
        DSR(fb0[6], vb0, 12288); DSR(fb0[7], vb0, 14336);

        // stage T+1 (vmcnt class; does not disturb lgkm counts)
        if (T + 1 < NK) STAGE(bo ^ 65536u, T + 1);

        WLG(4);  SB0();          // q0 frags ready (q1's 4 in flight)
        QUAD(fa0, fb0, 0)        // 32 MFMA

        // q2 issue: fa1 (8) + fb1[0..3] (4)
        RD_A(fa1, va1)
        DSR(fb1[0], vb1, 0);    DSR(fb1[1], vb1, 2048);
        DSR(fb1[2], vb1, 4096); DSR(fb1[3], vb1, 6144);

        WLG(12); SB0();          // q1 frags ready
        QUAD(fa0, fb0, 4)

        // q3 issue: fb1[4..7] (4)
        DSR(fb1[4], vb1, 8192);  DSR(fb1[5], vb1, 10240);
        DSR(fb1[6], vb1, 12288); DSR(fb1[7], vb1, 14336);

        WLG(4);  SB0();          // q2 frags ready
        QUAD(fa1, fb1, 0)

        WLG(0);  SB0();          // q3 frags ready
        QUAD(fa1, fb1, 4)

        WVM0();                  // T+1 staged loads landed (issued ~2000cyc ago)
        __builtin_amdgcn_s_barrier();
        SB0();
        bo ^= 65536u;
    }

    // ---- epilogue: row = m*16 + lr, col = n*16 + hi*4 + i (bf16x4 stores) ----
    const size_t crow0 = row0 + (size_t)(w >> 1) * 128;
    const int    ccol0 = col0 + (w & 1) * 128;
#pragma unroll
    for (int n = 0; n < 8; ++n) {
        float bbv[4] = {0.f, 0.f, 0.f, 0.f};
        if (GELU) {
            const float4 b4 = *(const float4*)(biasAll + (size_t)e * Ntot
                                               + ccol0 + n * 16 + hi * 4);
            bbv[0] = b4.x; bbv[1] = b4.y; bbv[2] = b4.z; bbv[3] = b4.w;
        }
#pragma unroll
        for (int m = 0; m < 8; ++m) {
            const f32x4 v = acc[m][n];
            bf16x4 o;
#pragma unroll
            for (int i = 0; i < 4; ++i) {
                float t = v[i];
                if (GELU) {
                    t += bbv[i];
                    const float u  = 0.7978845608028654f * (t + 0.044715f * t * t * t);
                    const float ex = __expf(2.f * u);
                    t = t * (1.f - 1.f / (ex + 1.f));   // 0.5t(1+tanh u)
                }
                o[i] = (__bf16)t;
            }
            *(bf16x4*)(Call + (crow0 + m * 16 + lr) * (size_t)Ntot
                       + ccol0 + n * 16 + hi * 4) = o;
        }
    }
}

// ---------------------------------------------------------------------------
// Combine: y[n][c] = sum_k gate * (out[slot][c] + b2[e][c]); writes all of y.
// ---------------------------------------------------------------------------
__global__ __launch_bounds__(256) void k_combine(
    const __bf16* __restrict__ outb, const int* __restrict__ slot,
    const float* __restrict__ gates, const int* __restrict__ tidx,
    const float* __restrict__ b2, float* __restrict__ y)
{
    const int n = blockIdx.x;
    const int t = threadIdx.x;
    const int c = t * 4;
    float r0 = 0.f, r1 = 0.f, r2 = 0.f, r3 = 0.f;
#pragma unroll
    for (int k = 0; k < KTOP; ++k) {
        const int s = slot[n * 2 + k];
        if (s < 0) continue;
        const float g = gates[n * 2 + k];
        const int   e = tidx[n * 2 + k];
        const bf16x4 v = *(const bf16x4*)(outb + (size_t)s * CDIM + c);
        const float4 bb = *(const float4*)(b2 + (size_t)e * CDIM + c);
        r0 += g * ((float)v[0] + bb.x);
        r1 += g * ((float)v[1] + bb.y);
        r2 += g * ((float)v[2] + bb.z);
        r3 += g * ((float)v[3] + bb.w);
    }
    float4 o = make_float4(r0, r1, r2, r3);
    *(float4*)(y + (size_t)n * CDIM + c) = o;
}

// ---------------------------------------------------------------------------
extern "C" void kernel_launch(void* const* d_in, const int* in_sizes, int n_in,
                              void* d_out, int out_size, void* d_ws, size_t ws_size,
                              hipStream_t stream)
{
    const float* x  = (const float*)d_in[0];
    const float* rw = (const float*)d_in[1];
    const float* rb = (const float*)d_in[2];
    const float* w1 = (const float*)d_in[3];
    const float* b1 = (const float*)d_in[4];
    const float* w2 = (const float*)d_in[5];
    const float* b2 = (const float*)d_in[6];
    float* y = (float*)d_out;

    char* ws = (char*)d_ws;
    size_t off = 0;
    auto alloc = [&](size_t bytes) -> void* {
        void* p = ws + off;
        off = (off + bytes + 255) & ~(size_t)255;
        return p;
    };
    __bf16* w1t  = (__bf16*)alloc((size_t)NE * CDIM * HDIM * 2);   // [E][H][C]
    __bf16* w2t  = (__bf16*)alloc((size_t)NE * CDIM * HDIM * 2);   // [E][C][H]
    __bf16* inp  = (__bf16*)alloc((size_t)NE * CAPE * CDIM * 2);   // [E*cap][C]
    __bf16* hbuf = (__bf16*)alloc((size_t)NE * CAPE * HDIM * 2);   // [E*cap][H]
    __bf16* outb = (__bf16*)alloc((size_t)NE * CAPE * CDIM * 2);   // [E*cap][C]
    float*  probs = (float*)alloc((size_t)NTOK * NE * 4);
    float*  gates = (float*)alloc((size_t)NTOK * 2 * 4);
    int*    tidx  = (int*)alloc((size_t)NTOK * 2 * 4);
    int*    slot  = (int*)alloc((size_t)NTOK * 2 * 4);
    int*    tok   = (int*)alloc((size_t)NE * CAPE * 4);

    // 1. weight conversion (transposed to B^T layout, bf16)
    k_transpose_bf16<<<dim3(HDIM / 32, CDIM / 32, NE), 256, 0, stream>>>(
        w1, w1t, CDIM, HDIM);
    k_transpose_bf16<<<dim3(CDIM / 32, HDIM / 32, NE), 256, 0, stream>>>(
        w2, w2t, HDIM, CDIM);

    // 2. router
    k_router<<<NTOK / 4, 256, 0, stream>>>(x, rw, rb, probs, gates, tidx);

    // 3. dispatch scan + aux loss (single block, exact FCFS order)
    k_scan<<<1, 256, 0, stream>>>(tidx, probs, slot, tok, y + (size_t)NTOK * CDIM);

    // 4. gather expert inputs (bf16)
    k_gather<<<NE * CAPE, 256, 0, stream>>>(x, tok, inp);

    // 5. expert FFN — 256^2 4-wave LDS-minimal MFMA GEMMs
    //    GEMM1: 40 m-tiles x 16 n-tiles = 640 blocks
    k_gemm4<true><<<dim3((NE * CAPE / 256) * (HDIM / 256)), 256, 0, stream>>>(
        inp, w1t, b1, hbuf, CDIM, HDIM, HDIM / 256, CAPE / 256);
    //    GEMM2: 40 x 4 = 160 blocks
    k_gemm4<false><<<dim3((NE * CAPE / 256) * (CDIM / 256)), 256, 0, stream>>>(
        hbuf, w2t, nullptr, outb, HDIM, CDIM, CDIM / 256, CAPE / 256);

    // 6. combine back to tokens (+aux already written by scan)
    k_combine<<<NTOK, 256, 0, stream>>>(outb, slot, gates, tidx, b2, y);
}

// Round 6
// 417.295 us; speedup vs baseline: 1.0953x; 1.0953x over previous
//
#include <hip/hip_runtime.h>
#include <hip/hip_bf16.h>
#include <math.h>

#define NE    8
#define KTOP  2
#define CDIM  1024
#define HDIM  4096
#define NTOK  8192
#define CAPE  1280
#define NSLOT (NTOK * KTOP)

typedef __bf16 bf16x8 __attribute__((ext_vector_type(8)));
typedef __bf16 bf16x4 __attribute__((ext_vector_type(4)));
typedef __bf16 bf16x2 __attribute__((ext_vector_type(2)));
typedef float  f32x4  __attribute__((ext_vector_type(4)));

#define GAS __attribute__((address_space(1)))
#define LAS __attribute__((address_space(3)))

// ---------------------------------------------------------------------------
// Transposing fp32 -> bf16 weight conversion: src [E][R][Cc] -> dst [E][Cc][R]
// ---------------------------------------------------------------------------
__global__ __launch_bounds__(256) void k_transpose_bf16(
    const float* __restrict__ src, __bf16* __restrict__ dst, int R, int Cc)
{
    __shared__ float tile[32][33];
    const int e  = blockIdx.z;
    const int cb = blockIdx.x * 32;
    const int rb = blockIdx.y * 32;
    const int t  = threadIdx.x;
    const int tx = t & 31, ty = t >> 5;
    const float* s = src + (size_t)e * R * Cc;
    __bf16*      d = dst + (size_t)e * R * Cc;
#pragma unroll
    for (int i = 0; i < 32; i += 8)
        tile[ty + i][tx] = s[(size_t)(rb + ty + i) * Cc + cb + tx];
    __syncthreads();
    const int op  = t & 15;      // src-row pair
    const int oc0 = t >> 4;      // out-row base (0..15)
#pragma unroll
    for (int j = 0; j < 2; ++j) {
        const int oc = oc0 + j * 16;
        bf16x2 v;
        v[0] = (__bf16)tile[op * 2][oc];
        v[1] = (__bf16)tile[op * 2 + 1][oc];
        *(bf16x2*)(d + (size_t)(cb + oc) * R + rb + op * 2) = v;
    }
}

// ---------------------------------------------------------------------------
// Router: fp32 logits -> softmax -> top2 -> normalized gates. 1 wave = 1 token.
// ---------------------------------------------------------------------------
__global__ __launch_bounds__(256) void k_router(
    const float* __restrict__ x, const float* __restrict__ rw,
    const float* __restrict__ rb, float* __restrict__ probs,
    float* __restrict__ gates, int* __restrict__ tidx)
{
    __shared__ float rws[NE * CDIM];
    const int tid = threadIdx.x;
    for (int i = tid; i < NE * CDIM / 4; i += 256)
        ((float4*)rws)[i] = ((const float4*)rw)[i];
    __syncthreads();

    const int wave = tid >> 6, lane = tid & 63;
    const int n = blockIdx.x * 4 + wave;
    const float* xr = x + (size_t)n * CDIM;

    float acc[NE];
#pragma unroll
    for (int e = 0; e < NE; ++e) acc[e] = 0.f;
    for (int j = 0; j < CDIM / 64; ++j) {
        const float xv = xr[j * 64 + lane];
#pragma unroll
        for (int e = 0; e < NE; ++e) acc[e] += xv * rws[e * CDIM + j * 64 + lane];
    }
#pragma unroll
    for (int off = 32; off > 0; off >>= 1) {
#pragma unroll
        for (int e = 0; e < NE; ++e) acc[e] += __shfl_down(acc[e], off);
    }
    if (lane == 0) {
        float mx = -1e30f;
#pragma unroll
        for (int e = 0; e < NE; ++e) { acc[e] += rb[e]; mx = fmaxf(mx, acc[e]); }
        float p[NE], s = 0.f;
#pragma unroll
        for (int e = 0; e < NE; ++e) { p[e] = expf(acc[e] - mx); s += p[e]; }
        const float inv = 1.f / s;
#pragma unroll
        for (int e = 0; e < NE; ++e) { p[e] *= inv; probs[(size_t)n * NE + e] = p[e]; }
        int   i1 = 0;  float v1 = p[0];
        int   i2 = -1; float v2 = -1.f;
#pragma unroll
        for (int e = 1; e < NE; ++e) {
            if (p[e] > v1)      { v2 = v1; i2 = i1; v1 = p[e]; i1 = e; }
            else if (p[e] > v2) { v2 = p[e]; i2 = e; }
        }
        const float gs = 1.f / (v1 + v2);
        gates[n * 2 + 0] = v1 * gs;  gates[n * 2 + 1] = v2 * gs;
        tidx[n * 2 + 0]  = i1;       tidx[n * 2 + 1]  = i2;
    }
}

// ---------------------------------------------------------------------------
// Single-block scan: exact slot-order ranks, capacity drop, tok_buf, aux loss.
// ---------------------------------------------------------------------------
__global__ __launch_bounds__(256) void k_scan(
    const int* __restrict__ tidx, const float* __restrict__ probs,
    int* __restrict__ slot, int* __restrict__ tok, float* __restrict__ d_aux)
{
    __shared__ int   lcnt[256][NE];
    __shared__ float ps[256][NE];
    const int t = threadIdx.x;

    for (int i = t; i < NE * CAPE; i += 256) tok[i] = 0;

    int c8[NE];
#pragma unroll
    for (int e = 0; e < NE; ++e) c8[e] = 0;
    const int per  = NSLOT / 256;   // 64
    const int base = t * per;
    for (int s = 0; s < per; ++s) c8[tidx[base + s]]++;
#pragma unroll
    for (int e = 0; e < NE; ++e) lcnt[t][e] = c8[e];

    float f8[NE];
#pragma unroll
    for (int e = 0; e < NE; ++e) f8[e] = 0.f;
    for (int n = t; n < NTOK; n += 256) {
        const float4 a = *(const float4*)(probs + (size_t)n * NE);
        const float4 b = *(const float4*)(probs + (size_t)n * NE + 4);
        f8[0] += a.x; f8[1] += a.y; f8[2] += a.z; f8[3] += a.w;
        f8[4] += b.x; f8[5] += b.y; f8[6] += b.z; f8[7] += b.w;
    }
#pragma unroll
    for (int e = 0; e < NE; ++e) ps[t][e] = f8[e];

    __syncthreads();

    int pre[NE], tot[NE];
#pragma unroll
    for (int e = 0; e < NE; ++e) { pre[e] = 0; tot[e] = 0; }
    for (int tt = 0; tt < 256; ++tt) {
#pragma unroll
        for (int e = 0; e < NE; ++e) {
            const int v = lcnt[tt][e];
            tot[e] += v;
            if (tt < t) pre[e] += v;
        }
    }
    for (int s = 0; s < per; ++s) {
        const int sg = base + s;
        const int e  = tidx[sg];
        const int p  = pre[e]++;
        if (p < CAPE) { slot[sg] = e * CAPE + p; tok[e * CAPE + p] = sg >> 1; }
        else          { slot[sg] = -1; }
    }
    if (t == 0) {
        float imp[NE], isum = 0.f, ld[NE], lsum = 0.f;
#pragma unroll
        for (int e = 0; e < NE; ++e) {
            float v = 0.f;
            for (int tt = 0; tt < 256; ++tt) v += ps[tt][e];
            imp[e] = v; isum += v;
        }
#pragma unroll
        for (int e = 0; e < NE; ++e) { ld[e] = fminf((float)tot[e], (float)CAPE); lsum += ld[e]; }
        float aux = 0.f;
#pragma unroll
        for (int e = 0; e < NE; ++e) aux += (imp[e] / isum) * (ld[e] / lsum);
        *d_aux = aux * (float)(NE * NE);
    }
}

// ---------------------------------------------------------------------------
// Gather tokens into dense per-expert buffers, fp32 -> bf16.
// ---------------------------------------------------------------------------
__global__ __launch_bounds__(256) void k_gather(
    const float* __restrict__ x, const int* __restrict__ tok,
    __bf16* __restrict__ inp)
{
    const int row = blockIdx.x;
    const int t   = threadIdx.x;
    const int tk  = tok[row];
    const float4 v = ((const float4*)(x + (size_t)tk * CDIM))[t];
    bf16x4 o;
    o[0] = (__bf16)v.x; o[1] = (__bf16)v.y; o[2] = (__bf16)v.z; o[3] = (__bf16)v.w;
    *(bf16x4*)(inp + (size_t)row * CDIM + t * 4) = o;
}

// ---------------------------------------------------------------------------
// 256x256 8-wave MFMA GEMM — faithful m201 8-phase port.
//   8 waves 2Mx4N, per-wave 128x64, BK=64, 2 K-tiles per iteration (8 phases).
//   Phase = {ds_read subtile (12 at q0 / 4 else); stage ONE half-tile (2x
//   global_load_lds); [lgkm(8) if 12 reads]; barrier; lgkm(0); setprio(1);
//   16 MFMA; setprio(0); [vmcnt(4) at phases 4,8]; barrier}.
//   Stage ring (verified retire schedule, 6 half-tiles deep):
//     p1:A1h0(T+1) p2:A1h1(T+1) p3:B0h0(T+2) p4:B0h1(T+2)+vm4
//     p5:A0h0(T+2) p6:A0h1(T+2) p7:B1h0(T+3) p8:B1h1(T+3)+vm4
//   Tail tiles clamp kt to NK-1 (re-stage, never read) to keep counts exact.
//   LDS 128KiB: A[buf][half] @0..64K, B @64K..128K, 16KB per half-tile.
//   XOR-swizzle byte^=(row&7)<<4 via pre-swizzled global source.
// ---------------------------------------------------------------------------
#define MFMA_BF16 __builtin_amdgcn_mfma_f32_16x16x32_bf16
#define DSR_I(dst, addr, IMM) \
    asm volatile("ds_read_b128 %0, %1 offset:" #IMM : "=v"(dst) : "v"(addr))
#define DSR(dst, addr, IMM) DSR_I(dst, addr, IMM)
#define WVM4() asm volatile("s_waitcnt vmcnt(4)" ::: "memory")
#define SB0()  __builtin_amdgcn_sched_barrier(0)

#define PH(RDB, OA0, OA1, MB, VA0, VA1, VB0, VB1, STG, VMW)                   \
    {                                                                         \
        if (RDB) {                                                            \
            DSR(fb[0][0], VB0, 0);    DSR(fb[0][1], VB1, 0);                  \
            DSR(fb[1][0], VB0, 2048); DSR(fb[1][1], VB1, 2048);               \
            DSR(fb[2][0], VB0, 4096); DSR(fb[2][1], VB1, 4096);               \
            DSR(fb[3][0], VB0, 6144); DSR(fb[3][1], VB1, 6144);               \
        }                                                                     \
        DSR(fa[0][0], VA0, OA0); DSR(fa[0][1], VA1, OA0);                     \
        DSR(fa[1][0], VA0, OA1); DSR(fa[1][1], VA1, OA1);                     \
        STG;                                                                  \
        if (RDB) { asm volatile("s_waitcnt lgkmcnt(8)" ::: "memory"); }       \
        __builtin_amdgcn_s_barrier();                                         \
        asm volatile("s_waitcnt lgkmcnt(0)" ::: "memory");                    \
        SB0();                                                                \
        __builtin_amdgcn_s_setprio(1);                                        \
        _Pragma("unroll")                                                     \
        for (int n = 0; n < 4; ++n) {                                         \
            acc[MB][n]   = MFMA_BF16(fb[n][0], fa[0][0], acc[MB][n], 0,0,0);  \
            acc[MB][n]   = MFMA_BF16(fb[n][1], fa[0][1], acc[MB][n], 0,0,0);  \
            acc[MB+1][n] = MFMA_BF16(fb[n][0], fa[1][0], acc[MB+1][n],0,0,0); \
            acc[MB+1][n] = MFMA_BF16(fb[n][1], fa[1][1], acc[MB+1][n],0,0,0); \
        }                                                                     \
        __builtin_amdgcn_s_setprio(0);                                        \
        VMW;                                                                  \
        __builtin_amdgcn_s_barrier();                                        \
        SB0();                                                                \
    }

template <bool GELU>
__global__ __launch_bounds__(512, 2) void k_gemm8(
    const __bf16* __restrict__ Aall, const __bf16* __restrict__ Ball,
    const float* __restrict__ biasAll, __bf16* __restrict__ Call,
    int Ktot, int Ntot, int NBN, int mtPerE)
{
    __shared__ char lds[131072];   // A: [buf][half] @0; B: @65536

    const int NK  = Ktot >> 6;
    const int NI  = NK >> 1;
    const int cpx = gridDim.x >> 3;                 // grid % 8 == 0 by caller
    const int id  = blockIdx.x;
    const int sid = (id & 7) * cpx + (id >> 3);     // bijective XCD swizzle
    const int bm  = sid / NBN, bn = sid % NBN;
    const int e   = bm / mtPerE;

    const size_t row0 = (size_t)bm * 256;
    const int    col0 = bn * 256;

    const int tid = threadIdx.x;
    const int w   = tid >> 6, l = tid & 63;
    const int wr  = w >> 2, wc = w & 3;             // 2M x 4N wave grid
    const int lr  = l & 15, hi = l >> 4;

    // ---- staging constants: thread covers chunk c = g*512 + tid,
    //      rloc = g*64 + (tid>>3), k-chunk = tid&7, pre-swizzled by rloc&7 ----
    const int srow = tid >> 3;                              // 0..63
    const int kf   = ((tid & 7) ^ (srow & 7)) << 3;         // swizzled k elems
    const __bf16* pA = Aall + (row0 + srow) * (size_t)Ktot + kf;
    const __bf16* pB = Ball + ((size_t)e * Ntot + col0 + srow) * (size_t)Ktot + kf;
    const unsigned L0 = (unsigned)(size_t)(LAS char*)lds;

    // LDS stage dest bases (HW adds lane*16): A[buf][half], B[buf][half]
    const unsigned sA00 = L0 +          w * 1024;
    const unsigned sA01 = sA00 + 16384;
    const unsigned sA10 = sA00 + 32768;
    const unsigned sA11 = sA00 + 49152;
    const unsigned sB00 = sA00 + 65536;
    const unsigned sB01 = sB00 + 16384;
    const unsigned sB10 = sB00 + 32768;
    const unsigned sB11 = sB00 + 49152;

    auto SH_A = [&](unsigned dbase, int half, int kt) {
        const __bf16* g = pA + (size_t)(half * 128) * Ktot + (size_t)kt * 64;
#pragma unroll
        for (int gg = 0; gg < 2; ++gg)
            __builtin_amdgcn_global_load_lds(
                (const GAS void*)(g + (size_t)gg * 64 * Ktot),
                (LAS void*)(size_t)(dbase + gg * 8192), 16, 0, 0);
    };
    auto SH_B = [&](unsigned dbase, int half, int kt) {
        const __bf16* g = pB + (size_t)(half * 128) * Ktot + (size_t)kt * 64;
#pragma unroll
        for (int gg = 0; gg < 2; ++gg)
            __builtin_amdgcn_global_load_lds(
                (const GAS void*)(g + (size_t)gg * 64 * Ktot),
                (LAS void*)(size_t)(dbase + gg * 8192), 16, 0, 0);
    };

    // ---- ds_read lane constants (swizzled): row = base + lr, row&7 = l&7 ----
    const unsigned swz = (l & 7) << 4;
    const unsigned kb0 = ((unsigned)(hi << 4)) ^ swz;        // k-half 0
    const unsigned kb1 = ((unsigned)(64 + (hi << 4))) ^ swz; // k-half 1
    const unsigned vA00 = L0 + (unsigned)(wr * 16384 + lr * 128) + kb0;
    const unsigned vA01 = L0 + (unsigned)(wr * 16384 + lr * 128) + kb1;
    const unsigned vA10 = vA00 + 32768, vA11 = vA01 + 32768;
    const unsigned vBb  = L0 + 65536
        + (unsigned)((wc >> 1) * 16384 + ((wc & 1) * 64 + lr) * 128);
    const unsigned vB00 = vBb + kb0, vB01 = vBb + kb1;
    const unsigned vB10 = vB00 + 32768, vB11 = vB01 + 32768;

    // ---- prologue: B0(0), A0(0), B1(1) staged; retire B0,A0; barrier ----
    SH_B(sB00, 0, 0); SH_B(sB01, 1, 0);
    SH_A(sA00, 0, 0); SH_A(sA01, 1, 0);
    SH_B(sB10, 0, 1); SH_B(sB11, 1, 1);
    WVM4();
    __builtin_amdgcn_s_barrier();
    SB0();

    f32x4 acc[8][4] = {};
    bf16x8 fa[2][2], fb[4][2];

    for (int i = 0; i < NI; ++i) {
        const int t1 = 2 * i + 1;
        const int t2 = (2 * i + 2 < NK) ? 2 * i + 2 : NK - 1;
        const int t3 = (2 * i + 3 < NK) ? 2 * i + 3 : NK - 1;
        // ---- tile 2i (buf0), phases 1-4 ----
        PH(1, 0,     2048,  0, vA00, vA01, vB00, vB01, SH_A(sA10, 0, t1), (void)0)
        PH(0, 4096,  6144,  2, vA00, vA01, vB00, vB01, SH_A(sA11, 1, t1), (void)0)
        PH(0, 8192,  10240, 4, vA00, vA01, vB00, vB01, SH_B(sB00, 0, t2), (void)0)
        PH(0, 12288, 14336, 6, vA00, vA01, vB00, vB01, SH_B(sB01, 1, t2), WVM4())
        // ---- tile 2i+1 (buf1), phases 5-8 ----
        PH(1, 0,     2048,  0, vA10, vA11, vB10, vB11, SH_A(sA00, 0, t2), (void)0)
        PH(0, 4096,  6144,  2, vA10, vA11, vB10, vB11, SH_A(sA01, 1, t2), (void)0)
        PH(0, 8192,  10240, 4, vA10, vA11, vB10, vB11, SH_B(sB10, 0, t3), (void)0)
        PH(0, 12288, 14336, 6, vA10, vA11, vB10, vB11, SH_B(sB11, 1, t3), WVM4())
    }

    // ---- epilogue: row = m*16 + lr, col = n*16 + hi*4 + i (bf16x4 stores) ----
    const size_t crow0 = row0 + (size_t)wr * 128;
    const int    ccol0 = col0 + wc * 64;
#pragma unroll
    for (int n = 0; n < 4; ++n) {
        float bbv[4] = {0.f, 0.f, 0.f, 0.f};
        if (GELU) {
            const float4 b4 = *(const float4*)(biasAll + (size_t)e * Ntot
                                               + ccol0 + n * 16 + hi * 4);
            bbv[0] = b4.x; bbv[1] = b4.y; bbv[2] = b4.z; bbv[3] = b4.w;
        }
#pragma unroll
        for (int m = 0; m < 8; ++m) {
            const f32x4 v = acc[m][n];
            bf16x4 o;
#pragma unroll
            for (int i = 0; i < 4; ++i) {
                float t = v[i];
                if (GELU) {
                    t += bbv[i];
                    const float u  = 0.7978845608028654f * (t + 0.044715f * t * t * t);
                    const float ex = __expf(2.f * u);
                    t = t * (1.f - 1.f / (ex + 1.f));   // 0.5t(1+tanh u)
                }
                o[i] = (__bf16)t;
            }
            *(bf16x4*)(Call + (crow0 + m * 16 + lr) * (size_t)Ntot
                       + ccol0 + n * 16 + hi * 4) = o;
        }
    }
}

// ---------------------------------------------------------------------------
// Combine: y[n][c] = sum_k gate * (out[slot][c] + b2[e][c]); writes all of y.
// ---------------------------------------------------------------------------
__global__ __launch_bounds__(256) void k_combine(
    const __bf16* __restrict__ outb, const int* __restrict__ slot,
    const float* __restrict__ gates, const int* __restrict__ tidx,
    const float* __restrict__ b2, float* __restrict__ y)
{
    const int n = blockIdx.x;
    const int t = threadIdx.x;
    const int c = t * 4;
    float r0 = 0.f, r1 = 0.f, r2 = 0.f, r3 = 0.f;
#pragma unroll
    for (int k = 0; k < KTOP; ++k) {
        const int s = slot[n * 2 + k];
        if (s < 0) continue;
        const float g = gates[n * 2 + k];
        const int   e = tidx[n * 2 + k];
        const bf16x4 v = *(const bf16x4*)(outb + (size_t)s * CDIM + c);
        const float4 bb = *(const float4*)(b2 + (size_t)e * CDIM + c);
        r0 += g * ((float)v[0] + bb.x);
        r1 += g * ((float)v[1] + bb.y);
        r2 += g * ((float)v[2] + bb.z);
        r3 += g * ((float)v[3] + bb.w);
    }
    float4 o = make_float4(r0, r1, r2, r3);
    *(float4*)(y + (size_t)n * CDIM + c) = o;
}

// ---------------------------------------------------------------------------
extern "C" void kernel_launch(void* const* d_in, const int* in_sizes, int n_in,
                              void* d_out, int out_size, void* d_ws, size_t ws_size,
                              hipStream_t stream)
{
    const float* x  = (const float*)d_in[0];
    const float* rw = (const float*)d_in[1];
    const float* rb = (const float*)d_in[2];
    const float* w1 = (const float*)d_in[3];
    const float* b1 = (const float*)d_in[4];
    const float* w2 = (const float*)d_in[5];
    const float* b2 = (const float*)d_in[6];
    float* y = (float*)d_out;

    char* ws = (char*)d_ws;
    size_t off = 0;
    auto alloc = [&](size_t bytes) -> void* {
        void* p = ws + off;
        off = (off + bytes + 255) & ~(size_t)255;
        return p;
    };
    __bf16* w1t  = (__bf16*)alloc((size_t)NE * CDIM * HDIM * 2);   // [E][H][C]
    __bf16* w2t  = (__bf16*)alloc((size_t)NE * CDIM * HDIM * 2);   // [E][C][H]
    __bf16* inp  = (__bf16*)alloc((size_t)NE * CAPE * CDIM * 2);   // [E*cap][C]
    __bf16* hbuf = (__bf16*)alloc((size_t)NE * CAPE * HDIM * 2);   // [E*cap][H]
    __bf16* outb = (__bf16*)alloc((size_t)NE * CAPE * CDIM * 2);   // [E*cap][C]
    float*  probs = (float*)alloc((size_t)NTOK * NE * 4);
    float*  gates = (float*)alloc((size_t)NTOK * 2 * 4);
    int*    tidx  = (int*)alloc((size_t)NTOK * 2 * 4);
    int*    slot  = (int*)alloc((size_t)NTOK * 2 * 4);
    int*    tok   = (int*)alloc((size_t)NE * CAPE * 4);

    // 1. weight conversion (transposed to B^T layout, bf16)
    k_transpose_bf16<<<dim3(HDIM / 32, CDIM / 32, NE), 256, 0, stream>>>(
        w1, w1t, CDIM, HDIM);
    k_transpose_bf16<<<dim3(CDIM / 32, HDIM / 32, NE), 256, 0, stream>>>(
        w2, w2t, HDIM, CDIM);

    // 2. router
    k_router<<<NTOK / 4, 256, 0, stream>>>(x, rw, rb, probs, gates, tidx);

    // 3. dispatch scan + aux loss (single block, exact FCFS order)
    k_scan<<<1, 256, 0, stream>>>(tidx, probs, slot, tok, y + (size_t)NTOK * CDIM);

    // 4. gather expert inputs (bf16)
    k_gather<<<NE * CAPE, 256, 0, stream>>>(x, tok, inp);

    // 5. expert FFN — 256^2 8-wave 8-phase MFMA GEMMs
    //    GEMM1: 40 m-tiles x 16 n-tiles = 640 blocks
    k_gemm8<true><<<dim3((NE * CAPE / 256) * (HDIM / 256)), 512, 0, stream>>>(
        inp, w1t, b1, hbuf, CDIM, HDIM, HDIM / 256, CAPE / 256);
    //    GEMM2: 40 x 4 = 160 blocks
    k_gemm8<false><<<dim3((NE * CAPE / 256) * (CDIM / 256)), 512, 0, stream>>>(
        hbuf, w2t, nullptr, outb, HDIM, CDIM, CDIM / 256, CAPE / 256);

    // 6. combine back to tokens (+aux already written by scan)
    k_combine<<<NTOK, 256, 0, stream>>>(outb, slot, gates, tidx, b2, y);
}